// Round 1
// 6778.822 us; speedup vs baseline: 1.9961x; 1.9961x over previous
//
#include <hip/hip_runtime.h>
#include <cmath>

namespace {
constexpr int Vv  = 10000;
constexpr int Ee  = 512;
constexpr int Hh  = 1024;
constexpr int Bb  = 128;
constexpr int Tt  = 64;
constexpr int CTX = 4096;
constexpr int Gg  = 4096;   // 4*H
constexpr int KIN1 = 4608;  // E + CTX
constexpr int TN  = 128;    // N tile per gemm block
constexpr int SL  = 8;      // K-slices for lstm/base gemms
constexpr int SV  = 2;      // K-slices for logits gemm
}

typedef __bf16 bf16x8 __attribute__((ext_vector_type(8)));
typedef float  f32x4  __attribute__((ext_vector_type(4)));

// ---- fp32 -> (hi,lo) bf16 split, RNE both halves --------------------------
__device__ __forceinline__ unsigned rne16(unsigned u) {
  return (u + 0x7FFFu + ((u >> 16) & 1u)) >> 16;
}
// packs two elements: hi = [bf16(x1)|bf16(x0)], lo = residual bf16 pair
__device__ __forceinline__ void split2(float x0, float x1,
                                       unsigned& hi, unsigned& lo) {
  const unsigned h0 = rne16(__float_as_uint(x0));
  const unsigned h1 = rne16(__float_as_uint(x1));
  hi = h0 | (h1 << 16);
  const float r0 = x0 - __uint_as_float(h0 << 16);
  const float r1 = x1 - __uint_as_float(h1 << 16);
  const unsigned l0 = rne16(__float_as_uint(r0));
  const unsigned l1 = rne16(__float_as_uint(r1));
  lo = l0 | (l1 << 16);
}

// ---------------------------------------------------------------------------
// Split-bf16 MFMA GEMM: partial[slice][0:128][n0:n0+128] =
//   A(fp32)[0:128][kslice] @ W(fp32)[n0:n0+128][kslice]^T
// Virtual K = concat of segment1 (A1/W1, K1 cols) and segment2 (A2/W2).
// 3-term emulation: Ahi*Bhi + Alo*Bhi + Ahi*Blo (error ~2^-18 per product).
// Block: 256 thr = 4 waves (2x2), wave tile 64x64 (4x4 16x16x32 fragments).
// ---------------------------------------------------------------------------
__global__ __launch_bounds__(256) void gemm_split_mfma(
    const float* __restrict__ A1, int lda1,
    const float* __restrict__ W1, int ldw1, int K1,
    const float* __restrict__ A2, int lda2,
    const float* __restrict__ W2, int ldw2, int K2,
    int nrows, int kPerSlice,
    float* __restrict__ partial, int ldp)
{
  (void)K2;
  __shared__ unsigned short Ah[128][40];   // +8 pad: conflict-free b128 reads
  __shared__ unsigned short Al[128][40];
  __shared__ unsigned short Wh[128][40];
  __shared__ unsigned short Wl[128][40];

  const int tid  = threadIdx.x;
  const int n0   = blockIdx.x * TN;
  const int ks   = blockIdx.y * kPerSlice;
  const int nc   = kPerSlice >> 5;
  float* __restrict__ pout = partial + (size_t)blockIdx.y * (size_t)Bb * ldp;

  const int lane = tid & 63;
  const int wm   = ((tid >> 6) >> 1) * 64;   // wave M offset (0/64)
  const int wn   = ((tid >> 6) & 1) * 64;    // wave N offset (0/64)
  const int sr   = tid >> 1;                 // staging row 0..127
  const int kh   = (tid & 1) << 4;           // staging k-half 0/16
  const bool wok = (n0 + sr) < nrows;

  f32x4 acc[4][4];
#pragma unroll
  for (int i = 0; i < 4; ++i)
#pragma unroll
    for (int j = 0; j < 4; ++j) acc[i][j] = f32x4{0.f, 0.f, 0.f, 0.f};

  float4 areg[4], wreg[4];
  auto load_chunk = [&](int kc) {
    const float* ap;
    const float* wp;
    if (kc < K1) {
      ap = A1 + (size_t)sr * lda1 + kc + kh;
      wp = W1 + (size_t)(n0 + sr) * ldw1 + kc + kh;
    } else {
      ap = A2 + (size_t)sr * lda2 + (kc - K1) + kh;
      wp = W2 + (size_t)(n0 + sr) * ldw2 + (kc - K1) + kh;
    }
#pragma unroll
    for (int q = 0; q < 4; ++q) areg[q] = *(const float4*)(ap + 4 * q);
    if (wok) {
#pragma unroll
      for (int q = 0; q < 4; ++q) wreg[q] = *(const float4*)(wp + 4 * q);
    } else {
#pragma unroll
      for (int q = 0; q < 4; ++q) wreg[q] = float4{0.f, 0.f, 0.f, 0.f};
    }
  };

  load_chunk(ks);   // software prefetch chunk 0

  for (int c = 0; c < nc; ++c) {
    __syncthreads();                       // prior compute done -> LDS free
    {
      unsigned hA[8], lA[8], hW[8], lW[8];
#pragma unroll
      for (int q = 0; q < 4; ++q) {
        split2(areg[q].x, areg[q].y, hA[2 * q], lA[2 * q]);
        split2(areg[q].z, areg[q].w, hA[2 * q + 1], lA[2 * q + 1]);
        split2(wreg[q].x, wreg[q].y, hW[2 * q], lW[2 * q]);
        split2(wreg[q].z, wreg[q].w, hW[2 * q + 1], lW[2 * q + 1]);
      }
      *(uint4*)&Ah[sr][kh]     = uint4{hA[0], hA[1], hA[2], hA[3]};
      *(uint4*)&Ah[sr][kh + 8] = uint4{hA[4], hA[5], hA[6], hA[7]};
      *(uint4*)&Al[sr][kh]     = uint4{lA[0], lA[1], lA[2], lA[3]};
      *(uint4*)&Al[sr][kh + 8] = uint4{lA[4], lA[5], lA[6], lA[7]};
      *(uint4*)&Wh[sr][kh]     = uint4{hW[0], hW[1], hW[2], hW[3]};
      *(uint4*)&Wh[sr][kh + 8] = uint4{hW[4], hW[5], hW[6], hW[7]};
      *(uint4*)&Wl[sr][kh]     = uint4{lW[0], lW[1], lW[2], lW[3]};
      *(uint4*)&Wl[sr][kh + 8] = uint4{lW[4], lW[5], lW[6], lW[7]};
    }
    if (c + 1 < nc) load_chunk(ks + ((c + 1) << 5));  // overlaps compute
    __syncthreads();

    const int koff = (lane >> 4) << 3;   // k offset within chunk (0/8/16/24)
    const int fr   = lane & 15;
    bf16x8 bh[4], bl[4];
#pragma unroll
    for (int nf = 0; nf < 4; ++nf) {
      bh[nf] = *(const bf16x8*)&Wh[wn + 16 * nf + fr][koff];
      bl[nf] = *(const bf16x8*)&Wl[wn + 16 * nf + fr][koff];
    }
#pragma unroll
    for (int mf = 0; mf < 4; ++mf) {
      const bf16x8 ah = *(const bf16x8*)&Ah[wm + 16 * mf + fr][koff];
      const bf16x8 al = *(const bf16x8*)&Al[wm + 16 * mf + fr][koff];
#pragma unroll
      for (int nf = 0; nf < 4; ++nf) {
        acc[mf][nf] = __builtin_amdgcn_mfma_f32_16x16x32_bf16(ah, bh[nf], acc[mf][nf], 0, 0, 0);
        acc[mf][nf] = __builtin_amdgcn_mfma_f32_16x16x32_bf16(al, bh[nf], acc[mf][nf], 0, 0, 0);
        acc[mf][nf] = __builtin_amdgcn_mfma_f32_16x16x32_bf16(ah, bl[nf], acc[mf][nf], 0, 0, 0);
      }
    }
  }

  // epilogue: C/D layout col=lane&15, row=4*(lane>>4)+q  (within 16x16 frag)
  const int r0 = wm + ((lane >> 4) << 2);
  const int c0 = n0 + wn + (lane & 15);
#pragma unroll
  for (int mf = 0; mf < 4; ++mf) {
#pragma unroll
    for (int nf = 0; nf < 4; ++nf) {
      if (n0 + wn + 16 * nf < nrows) {   // frag-granular guard (nrows%16==0)
        float* p = pout + (size_t)(r0 + 16 * mf) * ldp + (c0 + 16 * nf);
#pragma unroll
        for (int q = 0; q < 4; ++q) p[(size_t)q * ldp] = acc[mf][nf][q];
      }
    }
  }
}

// init: zero h1,h2,c1,c2 (4*B*H contiguous) and gather x0 = drop*emb[data[:,0]]
__global__ __launch_bounds__(256) void init_kernel(
    const int* __restrict__ data, const float* __restrict__ drop,
    const float* __restrict__ embW, float* __restrict__ zbuf,
    float* __restrict__ xcur)
{
  const int i = blockIdx.x * 256 + threadIdx.x;
  if (i < 4 * Bb * Hh) zbuf[i] = 0.f;
  if (i < Bb * Ee) {
    const int b = i >> 9, e = i & 511;
    const int idx = data[b * Tt];
    xcur[i] = drop[idx] * embW[(size_t)idx * Ee + e];
  }
}

// base1 = sum_s pl[s] + b_ih1 + b_hh1   (B x G)
__global__ __launch_bounds__(256) void base_combine(
    const float* __restrict__ pl, const float* __restrict__ b1,
    const float* __restrict__ b2, float* __restrict__ base1)
{
  const int i = blockIdx.x * 256 + threadIdx.x;   // < B*G
  const int g = i & (Gg - 1);
  float v = b1[g] + b2[g];
#pragma unroll
  for (int s = 0; s < SL; ++s) v += pl[(size_t)s * (Bb * Gg) + i];
  base1[i] = v;
}

// LSTM cell: gates = sum_s partial[s] + (base1 | b_a+b_b) -> h,c update
__global__ __launch_bounds__(256) void cell_kernel(
    const float* __restrict__ pl,
    const float* __restrict__ base1,
    const float* __restrict__ ba, const float* __restrict__ bb,
    float* __restrict__ h, float* __restrict__ c)
{
  const int i = blockIdx.x * 256 + threadIdx.x;   // < B*H
  const int b = i >> 10, hh = i & (Hh - 1);
  float vi, vf, vg, vo;
  if (base1 != nullptr) {
    const float* bp = base1 + (size_t)b * Gg + hh;
    vi = bp[0]; vf = bp[Hh]; vg = bp[2 * Hh]; vo = bp[3 * Hh];
  } else {
    vi = ba[hh] + bb[hh];
    vf = ba[Hh + hh] + bb[Hh + hh];
    vg = ba[2 * Hh + hh] + bb[2 * Hh + hh];
    vo = ba[3 * Hh + hh] + bb[3 * Hh + hh];
  }
  const size_t rb = (size_t)b * Gg + hh;
#pragma unroll
  for (int s = 0; s < SL; ++s) {
    const float* pp = pl + (size_t)s * (Bb * Gg) + rb;
    vi += pp[0]; vf += pp[Hh]; vg += pp[2 * Hh]; vo += pp[3 * Hh];
  }
  const float si = 1.f / (1.f + expf(-vi));
  const float sf = 1.f / (1.f + expf(-vf));
  const float so = 1.f / (1.f + expf(-vo));
  const float tg = tanhf(vg);
  const float cn = sf * c[i] + si * tg;
  c[i] = cn;
  h[i] = so * tanhf(cn);
}

// logits finalize + per-row argmax (first-max ties) + next-input gather
__global__ __launch_bounds__(256) void argmax_kernel(
    const float* __restrict__ pv, const float* __restrict__ b_out,
    const int* __restrict__ tf_mask_t, const int* __restrict__ data, int t,
    const float* __restrict__ drop, const float* __restrict__ embW,
    float* __restrict__ out_t, float* __restrict__ xcur)
{
  const int b = blockIdx.x;
  const int tid = threadIdx.x;
  const float* p0 = pv + (size_t)b * Vv;
  const float* p1 = pv + (size_t)(Bb + b) * Vv;
  float* orow = out_t + (size_t)b * Vv;
  float best = -3.0e38f;
  int bi = 0;
  for (int j = tid; j < Vv; j += 256) {
    const float v = p0[j] + p1[j] + b_out[j];
    orow[j] = v;
    if (v > best) { best = v; bi = j; }   // strict > keeps first max in stride
  }
  __shared__ float sv[256];
  __shared__ int si[256];
  sv[tid] = best; si[tid] = bi;
  __syncthreads();
  for (int s = 128; s > 0; s >>= 1) {
    if (tid < s) {
      const float v2 = sv[tid + s]; const int i2 = si[tid + s];
      if (v2 > sv[tid] || (v2 == sv[tid] && i2 < si[tid])) { sv[tid] = v2; si[tid] = i2; }
    }
    __syncthreads();
  }
  const int ind = si[0];
  const int mask = tf_mask_t[b];
  const int tfidx = data[b * Tt + t + 1];
  const float dm = drop[tfidx];
  for (int e = tid; e < Ee; e += 256) {
    // predicted path uses RAW emb_W; teacher-forced path uses masked emb
    xcur[(size_t)b * Ee + e] = (mask == 1) ? embW[(size_t)ind * Ee + e]
                                           : dm * embW[(size_t)tfidx * Ee + e];
  }
}

extern "C" void kernel_launch(void* const* d_in, const int* in_sizes, int n_in,
                              void* d_out, int out_size, void* d_ws, size_t ws_size,
                              hipStream_t stream) {
  (void)in_sizes; (void)n_in; (void)out_size; (void)ws_size;
  const float* h_n   = (const float*)d_in[0];
  const int*   data  = (const int*)d_in[1];
  const int*   tfm   = (const int*)d_in[2];
  const float* drop  = (const float*)d_in[3];
  const float* embW  = (const float*)d_in[4];
  const float* W_ih1 = (const float*)d_in[5];
  const float* W_hh1 = (const float*)d_in[6];
  const float* b_ih1 = (const float*)d_in[7];
  const float* b_hh1 = (const float*)d_in[8];
  const float* W_ih2 = (const float*)d_in[9];
  const float* W_hh2 = (const float*)d_in[10];
  const float* b_ih2 = (const float*)d_in[11];
  const float* b_hh2 = (const float*)d_in[12];
  const float* W_out = (const float*)d_in[13];
  const float* b_out = (const float*)d_in[14];
  float* out = (float*)d_out;

  // workspace (floats): h1|h2|c1|c2 (zeroed) | xcur | base1 | pl[SL][B][G] | pv[SV][B][V]
  float* ws    = (float*)d_ws;
  float* h1    = ws;
  float* h2    = ws + (size_t)Bb * Hh;
  // c1 at 2BH, c2 at 3BH (addressed via cell kernels below)
  float* c1    = ws + 2 * (size_t)Bb * Hh;
  float* c2    = ws + 3 * (size_t)Bb * Hh;
  float* xcur  = ws + 4 * (size_t)Bb * Hh;          // B*E
  float* base1 = xcur + (size_t)Bb * Ee;            // B*G
  float* pl    = base1 + (size_t)Bb * Gg;           // SL*B*G
  float* pv    = pl + (size_t)SL * Bb * Gg;         // SV*B*V

  init_kernel<<<(4 * Bb * Hh) / 256, 256, 0, stream>>>(data, drop, embW, ws, xcur);

  // base1 = h_n @ W_ih1[:,512:]^T + b_ih1 + b_hh1  (once, via MFMA K-split)
  gemm_split_mfma<<<dim3(Gg / TN, SL), 256, 0, stream>>>(
      h_n, CTX, W_ih1 + Ee, KIN1, CTX,
      nullptr, 0, nullptr, 0, 0,
      Gg, CTX / SL, pl, Gg);
  base_combine<<<(Bb * Gg) / 256, 256, 0, stream>>>(pl, b_ih1, b_hh1, base1);

  for (int t = 0; t < Tt - 1; ++t) {
    // layer 1: [xcur | h1] against [W_ih1[:,:512] | W_hh1]
    gemm_split_mfma<<<dim3(Gg / TN, SL), 256, 0, stream>>>(
        xcur, Ee, W_ih1, KIN1, Ee,
        h1, Hh, W_hh1, Hh, Hh,
        Gg, (Ee + Hh) / SL, pl, Gg);
    cell_kernel<<<(Bb * Hh) / 256, 256, 0, stream>>>(pl, base1, nullptr, nullptr, h1, c1);

    // layer 2: [h1 | h2] against [W_ih2 | W_hh2]
    gemm_split_mfma<<<dim3(Gg / TN, SL), 256, 0, stream>>>(
        h1, Hh, W_ih2, Hh, Hh,
        h2, Hh, W_hh2, Hh, Hh,
        Gg, (2 * Hh) / SL, pl, Gg);
    cell_kernel<<<(Bb * Hh) / 256, 256, 0, stream>>>(pl, nullptr, b_ih2, b_hh2, h2, c2);

    // logits partials, then finalize+argmax+gather in one pass
    gemm_split_mfma<<<dim3((Vv + TN - 1) / TN, SV), 256, 0, stream>>>(
        h2, Hh, W_out, Hh, Hh,
        nullptr, 0, nullptr, 0, 0,
        Vv, Hh / SV, pv, Vv);
    float* out_t = out + (size_t)t * Bb * Vv;
    argmax_kernel<<<Bb, 256, 0, stream>>>(pv, b_out, tfm + t * Bb, data, t,
                                          drop, embW, out_t, xcur);
  }
}